// Round 1
// baseline (458.712 us; speedup 1.0000x reference)
//
#include <hip/hip_runtime.h>

// Problem constants (match reference)
#define BATCH 8
#define CIN   64
#define COUT  64
#define Hdim  128
#define Wdim  128
#define KTAPS 9
#define HW    (Hdim * Wdim)

__global__ __launch_bounds__(256) void dcnv2_direct(
    const float* __restrict__ x,      // (B, CIN, H, W)
    const float* __restrict__ off,    // (B, 18, H, W)
    const float* __restrict__ msk,    // (B, 9, H, W)
    const float* __restrict__ wgt,    // (COUT, CIN, 3, 3)
    const float* __restrict__ bias,   // (COUT)
    float* __restrict__ out)          // (B, COUT, H, W)
{
    int p = blockIdx.x * 256 + threadIdx.x;   // 0 .. B*H*W-1
    int b  = p >> 14;                         // / (H*W)
    int hw = p & (HW - 1);
    int y  = hw >> 7;
    int xq = hw & (Wdim - 1);

    float acc[COUT];
#pragma unroll
    for (int o = 0; o < COUT; ++o) acc[o] = 0.0f;

    const float* xb   = x   + b * CIN * HW;
    const float* offb = off + b * 2 * KTAPS * HW + hw;
    const float* mb   = msk + b * KTAPS * HW + hw;

    for (int k = 0; k < KTAPS; ++k) {
        int ky = k / 3, kx = k % 3;
        float py = (float)(y  - 1 + ky) + offb[(2 * k + 0) * HW];
        float px = (float)(xq - 1 + kx) + offb[(2 * k + 1) * HW];
        float m  = mb[k * HW];

        float fy = floorf(py), fx = floorf(px);
        float ly = py - fy,    lx = px - fx;
        float hy = 1.0f - ly,  hx = 1.0f - lx;
        int y0 = (int)fy, x0 = (int)fx;
        int y1 = y0 + 1,  x1 = x0 + 1;

        float vy0 = (y0 >= 0 && y0 < Hdim) ? 1.0f : 0.0f;
        float vy1 = (y1 >= 0 && y1 < Hdim) ? 1.0f : 0.0f;
        float vx0 = (x0 >= 0 && x0 < Wdim) ? 1.0f : 0.0f;
        float vx1 = (x1 >= 0 && x1 < Wdim) ? 1.0f : 0.0f;

        float w00 = hy * hx * vy0 * vx0 * m;
        float w01 = hy * lx * vy0 * vx1 * m;
        float w10 = ly * hx * vy1 * vx0 * m;
        float w11 = ly * lx * vy1 * vx1 * m;

        int cy0 = min(max(y0, 0), Hdim - 1), cy1 = min(max(y1, 0), Hdim - 1);
        int cx0 = min(max(x0, 0), Wdim - 1), cx1 = min(max(x1, 0), Wdim - 1);
        int i00 = cy0 * Wdim + cx0, i01 = cy0 * Wdim + cx1;
        int i10 = cy1 * Wdim + cx0, i11 = cy1 * Wdim + cx1;

        const float* wk = wgt + k;          // + c*9 + o*576
        const float* xc = xb;
        for (int c = 0; c < CIN; ++c) {
            float val = w00 * xc[i00] + w01 * xc[i01]
                      + w10 * xc[i10] + w11 * xc[i11];
            const float* wc = wk + c * 9;
#pragma unroll
            for (int o = 0; o < COUT; ++o)
                acc[o] = fmaf(wc[o * (CIN * 9)], val, acc[o]);
            xc += HW;
        }
    }

    float* op = out + b * COUT * HW + hw;
#pragma unroll
    for (int o = 0; o < COUT; ++o)
        op[o * HW] = acc[o] + bias[o];
}

extern "C" void kernel_launch(void* const* d_in, const int* in_sizes, int n_in,
                              void* d_out, int out_size, void* d_ws, size_t ws_size,
                              hipStream_t stream) {
    const float* x    = (const float*)d_in[0];
    const float* off  = (const float*)d_in[1];
    const float* msk  = (const float*)d_in[2];
    const float* wgt  = (const float*)d_in[3];
    const float* bias = (const float*)d_in[4];
    float* out = (float*)d_out;

    int total = BATCH * HW;                 // 131072 threads, one per pixel
    dcnv2_direct<<<total / 256, 256, 0, stream>>>(x, off, msk, wgt, bias, out);
}

// Round 2
// 58.250 us; speedup vs baseline: 7.8748x; 7.8748x over previous
//
#include <hip/hip_runtime.h>

#define BATCH 8
#define CIN   64
#define COUT  64
#define Hdim  128
#define Wdim  128
#define HW    (Hdim * Wdim)

typedef unsigned short ushort_t;
typedef unsigned short ushort8 __attribute__((ext_vector_type(8)));
typedef short short8 __attribute__((ext_vector_type(8)));
typedef float f32x4 __attribute__((ext_vector_type(4)));

__device__ __forceinline__ float b2f(ushort_t u) {
    return __uint_as_float(((unsigned int)u) << 16);
}
__device__ __forceinline__ ushort_t f2b(float f) {
    unsigned int u = __float_as_uint(f);
    return (ushort_t)((u + 0x8000u) >> 16);
}

// ---------------- prep: x (B,C,H,W) f32 -> xt (B,H,W,C) bf16 ; w (O,C,3,3) f32 -> wt (9,O,C) bf16
__global__ __launch_bounds__(256) void dcnv2_prep(
    const float* __restrict__ x, const float* __restrict__ w,
    ushort_t* __restrict__ xt, ushort_t* __restrict__ wt)
{
    int bid = blockIdx.x;
    if (bid < 4096) {
        int g = bid * 256 + threadIdx.x;          // B*HW*8 = 1,048,576
        int pixel = g >> 3;
        int c0 = (g & 7) << 3;
        int b = pixel >> 14, hw = pixel & (HW - 1);
        const float* xp = x + (size_t)(b * CIN + c0) * HW + hw;
        ushort8 o;
#pragma unroll
        for (int i = 0; i < 8; ++i) o[i] = f2b(xp[(size_t)i * HW]);
        *(ushort8*)(xt + (size_t)pixel * 64 + c0) = o;
    } else {
        int t2 = (bid - 4096) * 256 + threadIdx.x; // 0..4095
        int o = t2 >> 6, c = t2 & 63;
        const float* wp = w + (size_t)(o * 64 + c) * 9;
#pragma unroll
        for (int k = 0; k < 9; ++k) wt[k * 4096 + o * 64 + c] = f2b(wp[k]);
    }
}

// ---------------- main: fused deformable-im2col + bf16 MFMA GEMM
// block = 256 thr (4 waves), 64 pixels/block, all 64 outputs, K=576 over 9 taps
__global__ __launch_bounds__(256) void dcnv2_mfma(
    const ushort_t* __restrict__ xt,   // (B,H,W,C) bf16
    const ushort_t* __restrict__ wt,   // (9,O,C) bf16
    const float* __restrict__ off,     // (B,18,H,W)
    const float* __restrict__ msk,     // (B,9,H,W)
    const float* __restrict__ bias,    // (O)
    float* __restrict__ out)           // (B,O,H,W)
{
    __shared__ ushort_t col[64 * 72];  // padded stride 72 bf16
    __shared__ ushort_t wl [64 * 72];

    int bid = blockIdx.x;
    int swz = (bid & 7) * 256 + (bid >> 3);   // XCD swizzle: batch -> one XCD (2048 % 8 == 0)
    int tid = threadIdx.x;
    int pbase = swz << 6;

    // sampling mapping: 4 threads per pixel, 16 channels each
    int p_loc = tid >> 2;
    int c0 = (tid & 3) << 4;
    int pixel = pbase + p_loc;
    int bb = pixel >> 14;
    int hw = pixel & (HW - 1);
    int y = hw >> 7, xq = hw & (Wdim - 1);

    // preload all offsets/mask (register arrays, fully unrolled indices)
    float oy[9], ox[9], mm[9];
    const float* offb = off + (size_t)(bb * 18) * HW + hw;
    const float* mb   = msk + (size_t)(bb * 9) * HW + hw;
#pragma unroll
    for (int k = 0; k < 9; ++k) {
        oy[k] = offb[(size_t)(2 * k)     * HW];
        ox[k] = offb[(size_t)(2 * k + 1) * HW];
        mm[k] = mb  [(size_t)k * HW];
    }
    const ushort_t* xtb = xt + (size_t)bb * HW * 64;

    // mfma mapping: wave wv owns pixel rows [wv*16, wv*16+16), all 64 outs
    int lane = tid & 63;
    int wv = tid >> 6;
    int arow = wv * 16 + (lane & 15);
    int kc8 = (lane >> 4) << 3;           // 0,8,16,24
    f32x4 zero4 = {0.f, 0.f, 0.f, 0.f};
    f32x4 acc[4];
#pragma unroll
    for (int n = 0; n < 4; ++n) acc[n] = zero4;

#pragma unroll
    for (int k = 0; k < 9; ++k) {
        const int ky = k / 3, kx = k % 3;
        __syncthreads();   // previous tap's LDS reads done

        // ---- stage W^k tile: thread: o=tid>>2, 16 channels
        {
            int o = tid >> 2;
            const ushort8* src = (const ushort8*)(wt + k * 4096 + o * 64 + c0);
            ushort8 w0 = src[0], w1 = src[1];
            *(ushort8*)(&wl[o * 72 + c0])     = w0;
            *(ushort8*)(&wl[o * 72 + c0 + 8]) = w1;
        }

        // ---- deformable bilinear sample, 16 channels
        {
            float py = (float)(y - 1 + ky) + oy[k];
            float px = (float)(xq - 1 + kx) + ox[k];
            float fy = floorf(py), fx = floorf(px);
            float ly = py - fy, lx = px - fx;
            float hy = 1.f - ly, hx = 1.f - lx;
            int y0 = (int)fy, x0 = (int)fx;
            int y1 = y0 + 1, x1 = x0 + 1;
            float m = mm[k];
            float vy0 = (y0 >= 0 && y0 < Hdim) ? m : 0.f;
            float vy1 = (y1 >= 0 && y1 < Hdim) ? m : 0.f;
            float vx0 = (x0 >= 0 && x0 < Wdim) ? 1.f : 0.f;
            float vx1 = (x1 >= 0 && x1 < Wdim) ? 1.f : 0.f;
            float w00 = hy * hx * vy0 * vx0, w01 = hy * lx * vy0 * vx1;
            float w10 = ly * hx * vy1 * vx0, w11 = ly * lx * vy1 * vx1;
            int cy0 = min(max(y0, 0), Hdim - 1), cy1 = min(max(y1, 0), Hdim - 1);
            int cx0 = min(max(x0, 0), Wdim - 1), cx1 = min(max(x1, 0), Wdim - 1);

            const ushort_t* p00 = xtb + ((cy0 << 7) + cx0) * 64 + c0;
            const ushort_t* p01 = xtb + ((cy0 << 7) + cx1) * 64 + c0;
            const ushort_t* p10 = xtb + ((cy1 << 7) + cx0) * 64 + c0;
            const ushort_t* p11 = xtb + ((cy1 << 7) + cx1) * 64 + c0;
            ushort8 a00 = *(const ushort8*)p00, b00 = *(const ushort8*)(p00 + 8);
            ushort8 a01 = *(const ushort8*)p01, b01 = *(const ushort8*)(p01 + 8);
            ushort8 a10 = *(const ushort8*)p10, b10 = *(const ushort8*)(p10 + 8);
            ushort8 a11 = *(const ushort8*)p11, b11 = *(const ushort8*)(p11 + 8);

            ushort8 o0, o1;
#pragma unroll
            for (int j = 0; j < 8; ++j) {
                float v0 = w00 * b2f(a00[j]);
                v0 = fmaf(w01, b2f(a01[j]), v0);
                v0 = fmaf(w10, b2f(a10[j]), v0);
                v0 = fmaf(w11, b2f(a11[j]), v0);
                float v1 = w00 * b2f(b00[j]);
                v1 = fmaf(w01, b2f(b01[j]), v1);
                v1 = fmaf(w10, b2f(b10[j]), v1);
                v1 = fmaf(w11, b2f(b11[j]), v1);
                o0[j] = f2b(v0);
                o1[j] = f2b(v1);
            }
            *(ushort8*)(&col[p_loc * 72 + c0])     = o0;
            *(ushort8*)(&col[p_loc * 72 + c0 + 8]) = o1;
        }

        __syncthreads();   // tiles ready

        // ---- MFMA: K=64 for this tap (2 k-steps of 32)
#pragma unroll
        for (int s = 0; s < 2; ++s) {
            short8 afrag = *(const short8*)(&col[arow * 72 + s * 32 + kc8]);
#pragma unroll
            for (int n = 0; n < 4; ++n) {
                short8 bfrag = *(const short8*)(&wl[(n * 16 + (lane & 15)) * 72 + s * 32 + kc8]);
                acc[n] = __builtin_amdgcn_mfma_f32_16x16x32_bf16(afrag, bfrag, acc[n], 0, 0, 0);
            }
        }
    }

    // ---- epilogue: D row = pixel (lane>>4)*4+j, col = out (lane&15)
    int hwb = pbase & (HW - 1);
    float* ob = out + ((size_t)bb << 6) * HW;
#pragma unroll
    for (int n = 0; n < 4; ++n) {
        int o = n * 16 + (lane & 15);
        float bv = bias[o];
#pragma unroll
        for (int j = 0; j < 4; ++j) {
            int ploc = wv * 16 + ((lane >> 4) << 2) + j;
            ob[((size_t)o << 14) + hwb + ploc] = acc[n][j] + bv;
        }
    }
}

// ---------------- fallback (round-1 direct kernel) if ws too small
__global__ __launch_bounds__(256) void dcnv2_direct(
    const float* __restrict__ x, const float* __restrict__ off,
    const float* __restrict__ msk, const float* __restrict__ wgt,
    const float* __restrict__ bias, float* __restrict__ out)
{
    int p = blockIdx.x * 256 + threadIdx.x;
    int b = p >> 14;
    int hw = p & (HW - 1);
    int y = hw >> 7;
    int xq = hw & (Wdim - 1);
    float acc[COUT];
#pragma unroll
    for (int o = 0; o < COUT; ++o) acc[o] = 0.0f;
    const float* xb = x + b * CIN * HW;
    const float* offb = off + b * 18 * HW + hw;
    const float* mb = msk + b * 9 * HW + hw;
    for (int k = 0; k < 9; ++k) {
        int ky = k / 3, kx = k % 3;
        float py = (float)(y - 1 + ky) + offb[(2 * k) * HW];
        float px = (float)(xq - 1 + kx) + offb[(2 * k + 1) * HW];
        float m = mb[k * HW];
        float fy = floorf(py), fx = floorf(px);
        float ly = py - fy, lx = px - fx;
        float hy = 1.0f - ly, hx = 1.0f - lx;
        int y0 = (int)fy, x0 = (int)fx;
        int y1 = y0 + 1, x1 = x0 + 1;
        float vy0 = (y0 >= 0 && y0 < Hdim) ? 1.f : 0.f;
        float vy1 = (y1 >= 0 && y1 < Hdim) ? 1.f : 0.f;
        float vx0 = (x0 >= 0 && x0 < Wdim) ? 1.f : 0.f;
        float vx1 = (x1 >= 0 && x1 < Wdim) ? 1.f : 0.f;
        float w00 = hy * hx * vy0 * vx0 * m, w01 = hy * lx * vy0 * vx1 * m;
        float w10 = ly * hx * vy1 * vx0 * m, w11 = ly * lx * vy1 * vx1 * m;
        int cy0 = min(max(y0, 0), Hdim - 1), cy1 = min(max(y1, 0), Hdim - 1);
        int cx0 = min(max(x0, 0), Wdim - 1), cx1 = min(max(x1, 0), Wdim - 1);
        int i00 = cy0 * Wdim + cx0, i01 = cy0 * Wdim + cx1;
        int i10 = cy1 * Wdim + cx0, i11 = cy1 * Wdim + cx1;
        const float* wk = wgt + k;
        const float* xc = xb;
        for (int c = 0; c < CIN; ++c) {
            float val = w00 * xc[i00] + w01 * xc[i01] + w10 * xc[i10] + w11 * xc[i11];
            const float* wc = wk + c * 9;
#pragma unroll
            for (int o = 0; o < COUT; ++o)
                acc[o] = fmaf(wc[o * (CIN * 9)], val, acc[o]);
            xc += HW;
        }
    }
    float* op = out + b * COUT * HW + hw;
#pragma unroll
    for (int o = 0; o < COUT; ++o) op[o * HW] = acc[o] + bias[o];
}

extern "C" void kernel_launch(void* const* d_in, const int* in_sizes, int n_in,
                              void* d_out, int out_size, void* d_ws, size_t ws_size,
                              hipStream_t stream) {
    const float* x    = (const float*)d_in[0];
    const float* off  = (const float*)d_in[1];
    const float* msk  = (const float*)d_in[2];
    const float* wgt  = (const float*)d_in[3];
    const float* bias = (const float*)d_in[4];
    float* out = (float*)d_out;

    const size_t xt_elems = (size_t)BATCH * HW * 64;   // 8,388,608 bf16
    const size_t wt_elems = 9 * 4096;                  // 36,864 bf16
    const size_t need = (xt_elems + wt_elems) * sizeof(ushort_t);

    if (ws_size < need) {
        dcnv2_direct<<<(BATCH * HW) / 256, 256, 0, stream>>>(x, off, msk, wgt, bias, out);
        return;
    }

    ushort_t* xt = (ushort_t*)d_ws;
    ushort_t* wt = xt + xt_elems;

    dcnv2_prep<<<4096 + 16, 256, 0, stream>>>(x, wgt, xt, wt);
    dcnv2_mfma<<<2048, 256, 0, stream>>>(xt, wt, off, msk, bias, out);
}